// Round 9
// baseline (4260.270 us; speedup 1.0000x reference)
//
#include <hip/hip_runtime.h>
#include <hip/hip_bf16.h>
#include <hip/hip_fp8.h>
#include <math.h>

// Encoder GRU, B=8192 T=256 H=512 — sync-free state-resident, v12.
// v8 protocol (per-wave flags, dbuf fp8 state, HW fp8 cvt, setprio) with the
// matmul moved to the MX-scaled MFMA at 2.29x rate:
//   v_mfma_scale_f32_32x32x64_f8f6f4 (fp8/fp8, all scales = 1.0 exactly)
//   - 8 phases of K=64; per wave 3 gate-tiles (z,r,h cols [w*32,+32))
//   - acc 3 x f32x16 = 48 (32x32 C/D: col=lane&31, row=(reg&3)+8*(reg>>2)
//     +4*(lane>>5) — HW-verified layout, dtype-independent)
//   - per-lane: ONE h-column (jc = w*32+(lane&31)), 16 rows, 7 consts
//   - B: rolling 3 tile-buffers (24 VGPR), refill tile tau right after its
//     MFMA with phase+1 data (~1-phase lookahead; phase-7 refill wraps to
//     next step, flying through the epilogue)
//   - A: 4x ds_read_b64 per phase (8-B-granule swizzle unchanged from v8)
// A/B fragment k-map: k = 32*(lane>>5) + byte, identical function on both
// operands -> correct under any HW k-permutation (MFMA layouts k-symmetric).
// Scales: E8M0 0x7F = 2^0 -> numerics identical to non-scaled fp8 MFMA.
// d_in: x(B,T), kmforenc(T), dense_kernel(1,H), dense_bias(H),
//       gru_kernel(H,3H), gru_recurrent(H,3H), gru_bias(2,3H)

constexpr int B_  = 8192;
constexpr int T_  = 256;
constexpr int H_  = 512;
constexpr int H3_ = 1536;
constexpr size_t BH = (size_t)B_ * H_;
constexpr int ROWS = 32;

typedef float f32x16 __attribute__((ext_vector_type(16)));
typedef int   i32x8  __attribute__((ext_vector_type(8)));
typedef int   i32x4  __attribute__((ext_vector_type(4)));

__device__ __forceinline__ unsigned char f2e4m3(float f) {
    __hip_fp8_e4m3 v(f); return v.__x;
}
// swizzled byte offset into one fp8 state plane [32 rows][512 cols]
__device__ __forceinline__ int swz(int row, int col) {
    return (row * 512 + col) ^ ((row & 15) << 3);
}
__device__ __forceinline__ float fast_sigmoid(float v) {
    return __builtin_amdgcn_rcpf(1.f + __expf(-v));
}
__device__ __forceinline__ float fast_tanh(float v) {
    float a = fabsf(v);
    float e = __expf(-2.f * a);
    float t = (1.f - e) * __builtin_amdgcn_rcpf(1.f + e);
    return copysignf(t, v);
}

// wx[j] = sum_h dense_kernel[h]*gru_kernel[h,j]
// cc[j] = sum_h dense_bias[h]*gru_kernel[h,j] + gru_bias[0][j]
__global__ void prep_wx(const float* __restrict__ dk,
                        const float* __restrict__ db,
                        const float* __restrict__ K,
                        const float* __restrict__ gb,
                        float* __restrict__ wx,
                        float* __restrict__ cc) {
    int j = blockIdx.x * blockDim.x + threadIdx.x;
    if (j >= H3_) return;
    float a = 0.f, c = 0.f;
    for (int h = 0; h < H_; ++h) {
        float kv = K[(size_t)h * H3_ + j];
        a = fmaf(dk[h], kv, a);
        c = fmaf(db[h], kv, c);
    }
    wx[j] = a;
    cc[j] = c + gb[j];
}

// Pack R (H x 3H row-major) into per-(ph,w,tau) 2 KB B-tile blocks for the
// 32x32x64 MFMA: lane L holds bytes [32L, 32L+32) of the block =
//   col n = tau*512 + w*32 + (L&31), k = ph*64 + 32*(L>>5) + e (e=0..31).
// Each thread packs one 8-byte octet: idx -> (blk, lane, octet).
__global__ void pack_Rf8(const float* __restrict__ R,
                         unsigned long long* __restrict__ Rp) {
    int idx  = blockIdx.x * 256 + threadIdx.x;    // < 98304 = 384 blk * 256
    int o8   = idx & 3;                           // octet within lane's 32 B
    int lane = (idx >> 2) & 63;
    int blk  = idx >> 8;                          // (ph*16 + w)*3 + tau
    int tau  = blk % 3;
    int rest = blk / 3;                           // ph*16 + w
    int w    = rest & 15;
    int ph   = rest >> 4;
    int n    = tau * 512 + w * 32 + (lane & 31);
    int k0   = ph * 64 + 32 * (lane >> 5) + o8 * 8;
    unsigned long long v = 0;
    #pragma unroll
    for (int e = 0; e < 8; ++e)
        v |= (unsigned long long)f2e4m3(R[(size_t)(k0 + e) * H3_ + n]) << (8 * e);
    Rp[(size_t)blk * 256 + lane * 4 + o8] = v;
}

__global__ __launch_bounds__(1024, 4) void gru_f8(
    const float* __restrict__ x, const float* __restrict__ km,
    const unsigned long long* __restrict__ Rp,
    const float* __restrict__ wx, const float* __restrict__ cc,
    const float* __restrict__ b1,
    float* __restrict__ out0, float* __restrict__ out1)
{
    __shared__ __align__(16) unsigned char st[2][ROWS * 512]; // dbuf fp8 state
    __shared__ float rkm[T_];
    __shared__ int flags[16];                     // steps completed per wave

    const int tid  = threadIdx.x;
    const int lane = tid & 63;
    const int w    = tid >> 6;                    // wave 0..15 -> cols [w*32,+32)
    const int l31  = lane & 31;
    const int hi   = lane >> 5;                   // 0/1
    const int row0 = blockIdx.x * ROWS;
    const bool odd1 = (lane & 1) != 0;
    const bool odd2 = (lane & 2) != 0;
    volatile int* vflag = (volatile int*)flags;
    constexpr int SC = 0x7F7F7F7F;                // E8M0 1.0 in every byte

    if (tid < T_) rkm[tid] = 1.f / km[tid];
    if (tid < 16) flags[tid] = 0;

    // per-thread gate constants — ONE h-column per lane
    const int jc = w * 32 + l31;
    const float wxzc = wx[jc], wxrc = wx[512 + jc], wxhc = wx[1024 + jc];
    const float czc  = cc[jc]        + b1[jc];
    const float crc  = cc[512 + jc]  + b1[512 + jc];
    const float cchc = cc[1024 + jc];
    const float b1hc = b1[1024 + jc];

    float hprev[16];
    #pragma unroll
    for (int r = 0; r < 16; ++r) hprev[r] = 0.f;

    // B stream: per-(ph,w,tau) 2 KB blocks; lane byte base = 32*lane.
    const char* wbc = (const char*)Rp + w * 6144 + lane * 32;
    // phase stride 16*3*2048 = 98304 B; tile stride 2048 B.

    __syncthreads();   // rkm + flags init visible (only barrier in kernel)

    // rolling tile buffers (2 x i32x4 each = 32 B)
    i32x4 B0a, B0b, B1a, B1b, B2a, B2b;
    B0a = *(const i32x4*)(wbc);            B0b = *(const i32x4*)(wbc + 16);
    B1a = *(const i32x4*)(wbc + 2048);     B1b = *(const i32x4*)(wbc + 2064);
    B2a = *(const i32x4*)(wbc + 4096);     B2b = *(const i32x4*)(wbc + 4112);

    #pragma unroll 1
    for (int t = 0; t < T_; ++t) {
        const char* rd = (const char*)st[t & 1];           // old state
        char*       wr = (char*)st[(t & 1) ^ 1];           // new state

        f32x16 acc0 = (f32x16)(0.f), acc1 = (f32x16)(0.f), acc2 = (f32x16)(0.f);

        if (t > 0) {
            #pragma unroll 1
            for (int ph = 0; ph < 8; ++ph) {
                // producers of state cols [ph*64, +64)
                while (vflag[2 * ph] < t || vflag[2 * ph + 1] < t)
                    __builtin_amdgcn_s_sleep(1);
                asm volatile("" ::: "memory");
                // A fragment: row = l31, k = ph*64 + 32*hi + 0..31
                const int c0 = ph * 64 + 32 * hi;
                long a0 = *(const long*)(rd + swz(l31, c0));
                long a1 = *(const long*)(rd + swz(l31, c0 + 8));
                long a2 = *(const long*)(rd + swz(l31, c0 + 16));
                long a3 = *(const long*)(rd + swz(l31, c0 + 24));
                i32x8 A;
                A[0] = (int)a0; A[1] = (int)(a0 >> 32);
                A[2] = (int)a1; A[3] = (int)(a1 >> 32);
                A[4] = (int)a2; A[5] = (int)(a2 >> 32);
                A[6] = (int)a3; A[7] = (int)(a3 >> 32);
                const char* nxt = wbc + (size_t)((ph + 1) & 7) * 98304;

                i32x8 Bv;
                __builtin_amdgcn_s_setprio(1);
                Bv[0]=B0a[0]; Bv[1]=B0a[1]; Bv[2]=B0a[2]; Bv[3]=B0a[3];
                Bv[4]=B0b[0]; Bv[5]=B0b[1]; Bv[6]=B0b[2]; Bv[7]=B0b[3];
                acc0 = __builtin_amdgcn_mfma_scale_f32_32x32x64_f8f6f4(
                    A, Bv, acc0, 0, 0, 0, SC, 0, SC);
                __builtin_amdgcn_s_setprio(0);
                B0a = *(const i32x4*)(nxt);        B0b = *(const i32x4*)(nxt + 16);

                __builtin_amdgcn_s_setprio(1);
                Bv[0]=B1a[0]; Bv[1]=B1a[1]; Bv[2]=B1a[2]; Bv[3]=B1a[3];
                Bv[4]=B1b[0]; Bv[5]=B1b[1]; Bv[6]=B1b[2]; Bv[7]=B1b[3];
                acc1 = __builtin_amdgcn_mfma_scale_f32_32x32x64_f8f6f4(
                    A, Bv, acc1, 0, 0, 0, SC, 0, SC);
                __builtin_amdgcn_s_setprio(0);
                B1a = *(const i32x4*)(nxt + 2048); B1b = *(const i32x4*)(nxt + 2064);

                __builtin_amdgcn_s_setprio(1);
                Bv[0]=B2a[0]; Bv[1]=B2a[1]; Bv[2]=B2a[2]; Bv[3]=B2a[3];
                Bv[4]=B2b[0]; Bv[5]=B2b[1]; Bv[6]=B2b[2]; Bv[7]=B2b[3];
                acc2 = __builtin_amdgcn_mfma_scale_f32_32x32x64_f8f6f4(
                    A, Bv, acc2, 0, 0, 0, SC, 0, SC);
                __builtin_amdgcn_s_setprio(0);
                B2a = *(const i32x4*)(nxt + 4096); B2b = *(const i32x4*)(nxt + 4112);
            }
        }

        // gates + state update. Lane l: col jc, rows (reg&3)+8*(reg>>2)+4*hi.
        const float rk = rkm[t];
        #pragma unroll
        for (int reg = 0; reg < 16; ++reg) {
            const int r = (reg & 3) + 8 * (reg >> 2) + 4 * hi;
            const float cb = ((t == 0)
                ? x[(size_t)(row0 + r) * T_]
                : __builtin_amdgcn_cvt_f32_fp8(
                      (int)*(const unsigned char*)(rd + swz(r, t)), 0)) * rk;
            float z   = fast_sigmoid(fmaf(cb, wxzc, czc) + acc0[reg]);
            float rg  = fast_sigmoid(fmaf(cb, wxrc, crc) + acc1[reg]);
            float mhh = acc2[reg] + b1hc;
            float hh  = fast_tanh(fmaf(rg, mhh, fmaf(cb, wxhc, cchc)));
            float hn  = fmaf(z, hprev[reg] - hh, hh);
            hprev[reg] = hn;
            // pack 4 consecutive cols (across lane quads, same hi) into a dword
            float nb = __shfl_xor(hn, 1);
            float lo = odd1 ? nb : hn;
            float hx = odd1 ? hn : nb;
            unsigned int w16 = (unsigned int)
                __builtin_amdgcn_cvt_pk_fp8_f32(lo, hx, 0, false);
            unsigned int v16 = (unsigned int)__shfl_xor((int)w16, 2);
            unsigned int w32 = (odd2 ? v16 : w16) | ((odd2 ? w16 : v16) << 16);
            if ((lane & 3) == 0)
                *(unsigned int*)(wr + swz(r, w * 32 + (l31 & ~3))) = w32;
        }

        // publish: all this wave's LDS reads/writes done, then raise flag.
        asm volatile("s_waitcnt lgkmcnt(0)" ::: "memory");
        if (lane == 0) vflag[w] = t + 1;
    }

    // final state from fp32 register carry -> both output halves
    #pragma unroll
    for (int reg = 0; reg < 16; ++reg) {
        const int r = (reg & 3) + 8 * (reg >> 2) + 4 * hi;
        size_t o = (size_t)(row0 + r) * H_ + jc;
        out0[o] = hprev[reg];
        out1[o] = hprev[reg];
    }
}

extern "C" void kernel_launch(void* const* d_in, const int* in_sizes, int n_in,
                              void* d_out, int out_size, void* d_ws, size_t ws_size,
                              hipStream_t stream) {
    const float* x  = (const float*)d_in[0];
    const float* km = (const float*)d_in[1];
    const float* dk = (const float*)d_in[2];
    const float* db = (const float*)d_in[3];
    const float* K  = (const float*)d_in[4];
    const float* R  = (const float*)d_in[5];
    const float* gb = (const float*)d_in[6];

    float* out  = (float*)d_out;
    float* out1 = out + BH;

    float* wx = (float*)d_ws;                     // 1536 f
    float* cc = wx + H3_;                         // 1536 f
    unsigned long long* Rp = (unsigned long long*)(cc + H3_);   // 768 KB

    prep_wx<<<dim3((H3_ + 255) / 256), 256, 0, stream>>>(dk, db, K, gb, wx, cc);
    pack_Rf8<<<dim3(384), 256, 0, stream>>>(R, Rp);

    gru_f8<<<dim3(256), dim3(1024), 0, stream>>>(
        x, km, Rp, wx, cc, gb + H3_, out, out1);
}

// Round 10
// 3525.812 us; speedup vs baseline: 1.2083x; 1.2083x over previous
//
#include <hip/hip_runtime.h>
#include <hip/hip_bf16.h>
#include <hip/hip_fp8.h>
#include <math.h>

// Encoder GRU, B=8192 T=256 H=512 — sync-free state-resident, v13.
// = v12 (MX-scaled mfma_scale_f32_32x32x64_f8f6f4 @2.29x rate, scales=1.0,
// per-wave flags, dbuf fp8 state, HW fp8 cvt, setprio) with the register
// budget fixed to fit 64 arch VGPRs (v12 spilled: FETCH 3.9GB):
//  (1) hprev fp32 carry moved to LDS (hlds, 64KB, [g][w*64+lane] float4
//      layout -> conflict-free b128; epilogue processes one g-group at a
//      time so only 4-8 hp regs are transiently live). Numerics unchanged.
//  (2) B tiles are i32x8 loaded directly (2x dwordx4) — no Bv copies.
// v12's MX datapath is kept verbatim (absmax was 0.0 — layout verified;
// MfmaUtil window matched the 2.8us scaled floor).
// d_in: x(B,T), kmforenc(T), dense_kernel(1,H), dense_bias(H),
//       gru_kernel(H,3H), gru_recurrent(H,3H), gru_bias(2,3H)

constexpr int B_  = 8192;
constexpr int T_  = 256;
constexpr int H_  = 512;
constexpr int H3_ = 1536;
constexpr size_t BH = (size_t)B_ * H_;
constexpr int ROWS = 32;

typedef float f32x16 __attribute__((ext_vector_type(16)));
typedef float f32x4f __attribute__((ext_vector_type(4)));
typedef int   i32x8  __attribute__((ext_vector_type(8)));

__device__ __forceinline__ unsigned char f2e4m3(float f) {
    __hip_fp8_e4m3 v(f); return v.__x;
}
// swizzled byte offset into one fp8 state plane [32 rows][512 cols]
__device__ __forceinline__ int swz(int row, int col) {
    return (row * 512 + col) ^ ((row & 15) << 3);
}
__device__ __forceinline__ float fast_sigmoid(float v) {
    return __builtin_amdgcn_rcpf(1.f + __expf(-v));
}
__device__ __forceinline__ float fast_tanh(float v) {
    float a = fabsf(v);
    float e = __expf(-2.f * a);
    float t = (1.f - e) * __builtin_amdgcn_rcpf(1.f + e);
    return copysignf(t, v);
}

// wx[j] = sum_h dense_kernel[h]*gru_kernel[h,j]
// cc[j] = sum_h dense_bias[h]*gru_kernel[h,j] + gru_bias[0][j]
__global__ void prep_wx(const float* __restrict__ dk,
                        const float* __restrict__ db,
                        const float* __restrict__ K,
                        const float* __restrict__ gb,
                        float* __restrict__ wx,
                        float* __restrict__ cc) {
    int j = blockIdx.x * blockDim.x + threadIdx.x;
    if (j >= H3_) return;
    float a = 0.f, c = 0.f;
    for (int h = 0; h < H_; ++h) {
        float kv = K[(size_t)h * H3_ + j];
        a = fmaf(dk[h], kv, a);
        c = fmaf(db[h], kv, c);
    }
    wx[j] = a;
    cc[j] = c + gb[j];
}

// Pack R (H x 3H row-major) into per-(ph,w,tau) 2 KB B-tile blocks for the
// 32x32x64 MFMA: lane L holds bytes [32L, 32L+32) of the block =
//   col n = tau*512 + w*32 + (L&31), k = ph*64 + 32*(L>>5) + e (e=0..31).
__global__ void pack_Rf8(const float* __restrict__ R,
                         unsigned long long* __restrict__ Rp) {
    int idx  = blockIdx.x * 256 + threadIdx.x;    // < 98304 = 384 blk * 256
    int o8   = idx & 3;                           // octet within lane's 32 B
    int lane = (idx >> 2) & 63;
    int blk  = idx >> 8;                          // (ph*16 + w)*3 + tau
    int tau  = blk % 3;
    int rest = blk / 3;                           // ph*16 + w
    int w    = rest & 15;
    int ph   = rest >> 4;
    int n    = tau * 512 + w * 32 + (lane & 31);
    int k0   = ph * 64 + 32 * (lane >> 5) + o8 * 8;
    unsigned long long v = 0;
    #pragma unroll
    for (int e = 0; e < 8; ++e)
        v |= (unsigned long long)f2e4m3(R[(size_t)(k0 + e) * H3_ + n]) << (8 * e);
    Rp[(size_t)blk * 256 + lane * 4 + o8] = v;
}

__global__ __launch_bounds__(1024, 4) void gru_f8(
    const float* __restrict__ x, const float* __restrict__ km,
    const unsigned long long* __restrict__ Rp,
    const float* __restrict__ wx, const float* __restrict__ cc,
    const float* __restrict__ b1,
    float* __restrict__ out0, float* __restrict__ out1)
{
    __shared__ __align__(16) unsigned char st[2][ROWS * 512]; // dbuf fp8 state
    __shared__ __align__(16) f32x4f hlds[4][1024];  // fp32 carry, 64 KB
    __shared__ float rkm[T_];
    __shared__ int flags[16];                     // steps completed per wave

    const int tid  = threadIdx.x;
    const int lane = tid & 63;
    const int w    = tid >> 6;                    // wave 0..15 -> cols [w*32,+32)
    const int l31  = lane & 31;
    const int hi   = lane >> 5;                   // 0/1
    const int row0 = blockIdx.x * ROWS;
    const bool odd1 = (lane & 1) != 0;
    const bool odd2 = (lane & 2) != 0;
    const int hslot = w * 64 + lane;              // per-thread hlds slot
    volatile int* vflag = (volatile int*)flags;
    constexpr int SC = 0x7F7F7F7F;                // E8M0 1.0 in every byte

    if (tid < T_) rkm[tid] = 1.f / km[tid];
    if (tid < 16) flags[tid] = 0;
    #pragma unroll
    for (int g = 0; g < 4; ++g)
        hlds[g][hslot] = (f32x4f){0.f, 0.f, 0.f, 0.f};

    // per-thread gate constants — ONE h-column per lane
    const int jc = w * 32 + l31;
    const float wxzc = wx[jc], wxrc = wx[512 + jc], wxhc = wx[1024 + jc];
    const float czc  = cc[jc]        + b1[jc];
    const float crc  = cc[512 + jc]  + b1[512 + jc];
    const float cchc = cc[1024 + jc];
    const float b1hc = b1[1024 + jc];

    // B stream: per-(ph,w,tau) 2 KB blocks; lane byte base = 32*lane.
    const char* wbc = (const char*)Rp + w * 6144 + lane * 32;
    // phase stride 16*3*2048 = 98304 B; tile stride 2048 B.

    __syncthreads();   // rkm + flags + hlds init visible (only barrier)

    // rolling tile buffers, loaded directly as i32x8 (2x dwordx4 each)
    i32x8 Bt0 = *(const i32x8*)(wbc);
    i32x8 Bt1 = *(const i32x8*)(wbc + 2048);
    i32x8 Bt2 = *(const i32x8*)(wbc + 4096);

    #pragma unroll 1
    for (int t = 0; t < T_; ++t) {
        const char* rd = (const char*)st[t & 1];           // old state
        char*       wr = (char*)st[(t & 1) ^ 1];           // new state

        f32x16 acc0 = (f32x16)(0.f), acc1 = (f32x16)(0.f), acc2 = (f32x16)(0.f);

        if (t > 0) {
            #pragma unroll 1
            for (int ph = 0; ph < 8; ++ph) {
                // producers of state cols [ph*64, +64)
                while (vflag[2 * ph] < t || vflag[2 * ph + 1] < t)
                    __builtin_amdgcn_s_sleep(1);
                asm volatile("" ::: "memory");
                // A fragment: row = l31, k = ph*64 + 32*hi + 0..31
                const int c0 = ph * 64 + 32 * hi;
                long a0 = *(const long*)(rd + swz(l31, c0));
                long a1 = *(const long*)(rd + swz(l31, c0 + 8));
                long a2 = *(const long*)(rd + swz(l31, c0 + 16));
                long a3 = *(const long*)(rd + swz(l31, c0 + 24));
                i32x8 A;
                A[0] = (int)a0; A[1] = (int)(a0 >> 32);
                A[2] = (int)a1; A[3] = (int)(a1 >> 32);
                A[4] = (int)a2; A[5] = (int)(a2 >> 32);
                A[6] = (int)a3; A[7] = (int)(a3 >> 32);
                const char* nxt = wbc + (size_t)((ph + 1) & 7) * 98304;

                __builtin_amdgcn_s_setprio(1);
                acc0 = __builtin_amdgcn_mfma_scale_f32_32x32x64_f8f6f4(
                    A, Bt0, acc0, 0, 0, 0, SC, 0, SC);
                __builtin_amdgcn_s_setprio(0);
                Bt0 = *(const i32x8*)(nxt);

                __builtin_amdgcn_s_setprio(1);
                acc1 = __builtin_amdgcn_mfma_scale_f32_32x32x64_f8f6f4(
                    A, Bt1, acc1, 0, 0, 0, SC, 0, SC);
                __builtin_amdgcn_s_setprio(0);
                Bt1 = *(const i32x8*)(nxt + 2048);

                __builtin_amdgcn_s_setprio(1);
                acc2 = __builtin_amdgcn_mfma_scale_f32_32x32x64_f8f6f4(
                    A, Bt2, acc2, 0, 0, 0, SC, 0, SC);
                __builtin_amdgcn_s_setprio(0);
                Bt2 = *(const i32x8*)(nxt + 4096);
            }
        }

        // gates + state update, one g-group (4 rows) at a time.
        // Lane: col jc, rows r = (reg&3) + 8*(reg>>2) + 4*hi, reg = g*4+j.
        const float rk = rkm[t];
        #pragma unroll
        for (int g = 0; g < 4; ++g) {
            f32x4f hp = hlds[g][hslot];
            f32x4f np;
            #pragma unroll
            for (int j = 0; j < 4; ++j) {
                const int reg = g * 4 + j;
                const int r   = j + 8 * g + 4 * hi;
                const float cb = ((t == 0)
                    ? x[(size_t)(row0 + r) * T_]
                    : __builtin_amdgcn_cvt_f32_fp8(
                          (int)*(const unsigned char*)(rd + swz(r, t)), 0)) * rk;
                const float az = (g == 0) ? acc0[ (0*4)+j ] : (g == 1) ? acc0[(1*4)+j]
                               : (g == 2) ? acc0[(2*4)+j] : acc0[(3*4)+j];
                const float ar = (g == 0) ? acc1[ (0*4)+j ] : (g == 1) ? acc1[(1*4)+j]
                               : (g == 2) ? acc1[(2*4)+j] : acc1[(3*4)+j];
                const float ah = (g == 0) ? acc2[ (0*4)+j ] : (g == 1) ? acc2[(1*4)+j]
                               : (g == 2) ? acc2[(2*4)+j] : acc2[(3*4)+j];
                float z   = fast_sigmoid(fmaf(cb, wxzc, czc) + az);
                float rg  = fast_sigmoid(fmaf(cb, wxrc, crc) + ar);
                float mhh = ah + b1hc;
                float hh  = fast_tanh(fmaf(rg, mhh, fmaf(cb, wxhc, cchc)));
                float hn  = fmaf(z, hp[j] - hh, hh);
                np[j] = hn;
                // pack 4 consecutive cols (across lane quads) into a dword
                float nb = __shfl_xor(hn, 1);
                float lo = odd1 ? nb : hn;
                float hx = odd1 ? hn : nb;
                unsigned int w16 = (unsigned int)
                    __builtin_amdgcn_cvt_pk_fp8_f32(lo, hx, 0, false);
                unsigned int v16 = (unsigned int)__shfl_xor((int)w16, 2);
                unsigned int w32 = (odd2 ? v16 : w16) | ((odd2 ? w16 : v16) << 16);
                if ((lane & 3) == 0)
                    *(unsigned int*)(wr + swz(r, w * 32 + (l31 & ~3))) = w32;
            }
            hlds[g][hslot] = np;
        }

        // publish: all this wave's LDS reads/writes done, then raise flag.
        asm volatile("s_waitcnt lgkmcnt(0)" ::: "memory");
        if (lane == 0) vflag[w] = t + 1;
    }

    // final state from fp32 LDS carry -> both output halves
    #pragma unroll
    for (int g = 0; g < 4; ++g) {
        f32x4f hp = hlds[g][hslot];
        #pragma unroll
        for (int j = 0; j < 4; ++j) {
            const int r = j + 8 * g + 4 * hi;
            size_t o = (size_t)(row0 + r) * H_ + jc;
            out0[o] = hp[j];
            out1[o] = hp[j];
        }
    }
}

extern "C" void kernel_launch(void* const* d_in, const int* in_sizes, int n_in,
                              void* d_out, int out_size, void* d_ws, size_t ws_size,
                              hipStream_t stream) {
    const float* x  = (const float*)d_in[0];
    const float* km = (const float*)d_in[1];
    const float* dk = (const float*)d_in[2];
    const float* db = (const float*)d_in[3];
    const float* K  = (const float*)d_in[4];
    const float* R  = (const float*)d_in[5];
    const float* gb = (const float*)d_in[6];

    float* out  = (float*)d_out;
    float* out1 = out + BH;

    float* wx = (float*)d_ws;                     // 1536 f
    float* cc = wx + H3_;                         // 1536 f
    unsigned long long* Rp = (unsigned long long*)(cc + H3_);   // 768 KB

    prep_wx<<<dim3((H3_ + 255) / 256), 256, 0, stream>>>(dk, db, K, gb, wx, cc);
    pack_Rf8<<<dim3(384), 256, 0, stream>>>(R, Rp);

    gru_f8<<<dim3(256), dim3(1024), 0, stream>>>(
        x, km, Rp, wx, cc, gb + H3_, out, out1);
}